// Round 6
// baseline (172.975 us; speedup 1.0000x reference)
//
#include <hip/hip_runtime.h>
#include <stdint.h>

// ---------------------------------------------------------------------------
// AttentionHead: out = softmax_causal((Xq WQ)(Xk WK)^T / sqrt(D)) (Xv WV)
// B=4, S=2048, D=1024.  bf16 MFMA, f32 accumulate.
// Round 6: single-wait-point K-loop (stage whole next tile at top, counted
// vmcnt<SA>, full-iteration in-flight) + quadrant-phase MFMA interleave
// (m201 discipline).  scores re-tiled to 128x128 x544 blocks (2/CU, one
// round + tail instead of 144 blocks on 256 CUs).
// ---------------------------------------------------------------------------

typedef __attribute__((ext_vector_type(8))) short short8;
typedef __attribute__((ext_vector_type(8))) unsigned short ushort8;
typedef __attribute__((ext_vector_type(4))) float f32x4;

__device__ __forceinline__ unsigned short f2bf(float f) {
  union { float f; unsigned u; } v; v.f = f;
  unsigned u = v.u + 0x7FFFu + ((v.u >> 16) & 1u);   // RNE
  return (unsigned short)(u >> 16);
}
__device__ __forceinline__ float bf2f(unsigned short h) {
  union { unsigned u; float f; } v; v.u = ((unsigned)h) << 16;
  return v.f;
}

__device__ __forceinline__ void gload16(const void* g, void* l) {
  __builtin_amdgcn_global_load_lds(
      (const __attribute__((address_space(1))) unsigned int*)g,
      (__attribute__((address_space(3))) unsigned int*)l, 16, 0, 0);
}

template<int N> __device__ __forceinline__ void vmwait() {
  static_assert(N >= 0 && N <= 16, "vmcnt range");
  if constexpr (N == 0) asm volatile("s_waitcnt vmcnt(0)" ::: "memory");
  else if constexpr (N == 1) asm volatile("s_waitcnt vmcnt(1)" ::: "memory");
  else if constexpr (N == 2) asm volatile("s_waitcnt vmcnt(2)" ::: "memory");
  else if constexpr (N == 3) asm volatile("s_waitcnt vmcnt(3)" ::: "memory");
  else if constexpr (N == 4) asm volatile("s_waitcnt vmcnt(4)" ::: "memory");
  else if constexpr (N == 5) asm volatile("s_waitcnt vmcnt(5)" ::: "memory");
  else if constexpr (N == 6) asm volatile("s_waitcnt vmcnt(6)" ::: "memory");
  else if constexpr (N == 7) asm volatile("s_waitcnt vmcnt(7)" ::: "memory");
  else if constexpr (N == 8) asm volatile("s_waitcnt vmcnt(8)" ::: "memory");
  else if constexpr (N == 10) asm volatile("s_waitcnt vmcnt(10)" ::: "memory");
  else if constexpr (N == 12) asm volatile("s_waitcnt vmcnt(12)" ::: "memory");
  else asm volatile("s_waitcnt vmcnt(16)" ::: "memory");
}
__device__ __forceinline__ void barrier_() { asm volatile("s_barrier" ::: "memory"); }
__device__ __forceinline__ void lgkm0() { asm volatile("s_waitcnt lgkmcnt(0)" ::: "memory"); }

// ---------------- f32 -> bf16 convert, 3 tensors fused ----------------------
__global__ __launch_bounds__(256)
void cvt3_bf16(const float* __restrict__ Xq, const float* __restrict__ Xk,
               const float* __restrict__ Xv,
               unsigned short* __restrict__ Oq, unsigned short* __restrict__ Ok,
               unsigned short* __restrict__ Ov) {
  const int bx = blockIdx.x;
  const int op = bx >> 12, r = bx & 4095;          // 4096 blocks per tensor
  const float* in = op == 0 ? Xq : op == 1 ? Xk : Xv;
  unsigned short* out = op == 0 ? Oq : op == 1 ? Ok : Ov;
  const long i = ((long)r * 256 + threadIdx.x) * 8;
  float4 a = *(const float4*)(in + i);
  float4 b = *(const float4*)(in + i + 4);
  ushort8 rr;
  rr[0] = f2bf(a.x); rr[1] = f2bf(a.y); rr[2] = f2bf(a.z); rr[3] = f2bf(a.w);
  rr[4] = f2bf(b.x); rr[5] = f2bf(b.y); rr[6] = f2bf(b.z); rr[7] = f2bf(b.w);
  *(ushort8*)(out + i) = rr;
}

// ---------------- weight transpose x3: WT[e][k] = W[k][e]*scale -------------
__global__ __launch_bounds__(256)
void wtrans3(const float* __restrict__ WQ, const float* __restrict__ WK,
             const float* __restrict__ WV,
             unsigned short* __restrict__ WQT, unsigned short* __restrict__ WKT,
             unsigned short* __restrict__ WVT) {
  const int z = blockIdx.z;
  const float* W = z == 0 ? WQ : z == 1 ? WK : WV;
  unsigned short* WT = z == 0 ? WQT : z == 1 ? WKT : WVT;
  const float scale = z == 0 ? 0.03125f : 1.0f;    // 1/sqrt(1024) into WQT
  __shared__ float t[32][33];
  const int bk = blockIdx.x * 32, be = blockIdx.y * 32;
  const int tx = threadIdx.x, ty = threadIdx.y;    // (32,8)
#pragma unroll
  for (int j = 0; j < 32; j += 8)
    t[ty + j][tx] = W[(long)(bk + ty + j) * 1024 + (be + tx)];
  __syncthreads();
#pragma unroll
  for (int j = 0; j < 32; j += 8)
    WT[(long)(be + ty + j) * 1024 + (bk + tx)] = f2bf(t[tx][ty + j] * scale);
}

// ---------------- B^T-layout bf16 GEMM: single-wait K-loop + quadrant phases
// C[m][n] = sum_k A[m][k]*B[n][k].  BM=MF*32, BN=NF*64.  8 waves (2Mx4N).
// LDS (caller-provided): [buf][khalf][row][32]; 16B-slot swizzle ^(row>>1)&3.
template<typename CT, int MF, int NF>
__device__ __forceinline__ void gemm_body(const unsigned short* __restrict__ A,
                                          const unsigned short* __restrict__ B,
                                          CT* __restrict__ C,
                                          int bm, int bn, int kmax,
                                          int lda, int ldb, int ldc,
                                          char* AL, char* BL) {
  constexpr int BM = MF * 32, BN = NF * 64;
  constexpr int LA = BM / 128, LB = BN / 128;      // gloads per k-half
  constexpr int SA = 2 * (LA + LB);                // gloads per K-tile
  constexpr int NH = (NF >= 4) ? 2 : 1;            // N-halves per phase grid
  constexpr int NS = NF / NH;                      // N-frags per phase

  const int tid = threadIdx.x;                     // 0..511
  const int lane = tid & 63, wid = tid >> 6;
  const int wr = wid >> 2, wc = wid & 3;           // 2x4 wave grid
  const int fr = lane & 15, fq = lane >> 4;
  const int srow = tid >> 2;                       // staging row 0..127
  const int scol = (((tid & 3) ^ ((tid >> 3) & 3)) << 3);  // pre-swz src col
  const int m0 = bm * BM, n0 = bn * BN;
  const int nt = kmax >> 6;

  f32x4 acc[MF][NF] = {};

  const unsigned short* As = A + (long)(m0 + srow) * lda + scol;
  const unsigned short* Bs = B + (long)(n0 + srow) * ldb + scol;

  // stage one full K-tile kt into buf b; issue order A-k0,B-k0,A-k1,B-k1
  auto stageTile = [&](int b, int kt) {
#pragma unroll
    for (int h = 0; h < 2; ++h) {
#pragma unroll
      for (int l = 0; l < LA; ++l)
        gload16(As + (long)l * 128 * lda + kt * 64 + h * 32,
                AL + b * (BM * 128) + h * (BM * 64) + l * 8192 + tid * 16);
#pragma unroll
      for (int l = 0; l < LB; ++l)
        gload16(Bs + (long)l * 128 * ldb + kt * 64 + h * 32,
                BL + b * (BN * 128) + h * (BN * 64) + l * 8192 + tid * 16);
    }
  };

  const int aoff = (wr * (BM / 2) + fr) * 64 + ((fq ^ ((fr >> 1) & 3)) << 4);
  const int boff = (wc * (BN / 4) + fr) * 64 + ((fq ^ ((fr >> 1) & 3)) << 4);
  auto ardf = [&](int b, int kk, int m) -> short8 {
    return *(const short8*)(AL + b * (BM * 128) + kk * (BM * 64) + aoff + m * 1024);
  };
  auto brdf = [&](int b, int kk, int n) -> short8 {
    return *(const short8*)(BL + b * (BN * 128) + kk * (BN * 64) + boff + n * 1024);
  };

  stageTile(0, 0);                                 // prologue

  for (int u = 0; u < nt; ++u) {
    const int cb = u & 1, nb = cb ^ 1;
    lgkm0();                                 // my reads of buf[nb] serviced
    barrier_();                              // all waves done with buf[nb]
    if (u + 1 < nt) { stageTile(nb, u + 1); vmwait<SA>(); }  // retire tile u
    else            { vmwait<0>(); }
    barrier_();                              // tile u resident for all waves
    // quadrant phases: (mh, nh) — each 2*(MF/2)*NS MFMA, fine interleave
#pragma unroll
    for (int mh = 0; mh < 2; ++mh) {
#pragma unroll
      for (int nh = 0; nh < NH; ++nh) {
        short8 a0[MF / 2], a1[MF / 2], b0[NS], b1[NS];
#pragma unroll
        for (int m = 0; m < MF / 2; ++m) {
          a0[m] = ardf(cb, 0, mh * (MF / 2) + m);
          a1[m] = ardf(cb, 1, mh * (MF / 2) + m);
        }
#pragma unroll
        for (int n = 0; n < NS; ++n) {
          b0[n] = brdf(cb, 0, nh * NS + n);
          b1[n] = brdf(cb, 1, nh * NS + n);
        }
        __builtin_amdgcn_s_setprio(1);
#pragma unroll
        for (int m = 0; m < MF / 2; ++m) {
#pragma unroll
          for (int n = 0; n < NS; ++n) {
            const int M = mh * (MF / 2) + m, N = nh * NS + n;
            acc[M][N] = __builtin_amdgcn_mfma_f32_16x16x32_bf16(a0[m], b0[n], acc[M][N], 0, 0, 0);
            acc[M][N] = __builtin_amdgcn_mfma_f32_16x16x32_bf16(a1[m], b1[n], acc[M][N], 0, 0, 0);
          }
        }
        __builtin_amdgcn_s_setprio(0);
        if (!(mh == 1 && nh == NH - 1)) barrier_();   // align phases
      }
    }
  }

  // C/D layout: col = lane&15, row = (lane>>4)*4 + reg
#pragma unroll
  for (int m = 0; m < MF; ++m) {
    const int row = m0 + wr * (BM / 2) + m * 16 + fq * 4;
#pragma unroll
    for (int n = 0; n < NF; ++n) {
      const int col = n0 + wc * (BN / 4) + n * 16 + fr;
#pragma unroll
      for (int r = 0; r < 4; ++r) {
        float v = acc[m][n][r];
        if constexpr (sizeof(CT) == 2)
          C[(long)(row + r) * ldc + col] = (CT)f2bf(v);
        else
          C[(long)(row + r) * ldc + col] = (CT)v;
      }
    }
  }
}

// Persistent Q/K + VT: 256 blocks.  Each block: one 256^2 Q-or-K tile
// (K=1024), then one 128x256 VT half-tile.  1.5 T_block each, no tail.
__global__ __launch_bounds__(512, 2)
void qkvt_gemm(const unsigned short* __restrict__ Xq, const unsigned short* __restrict__ WQT,
               unsigned short* __restrict__ Q,
               const unsigned short* __restrict__ Xk, const unsigned short* __restrict__ WKT,
               unsigned short* __restrict__ Kk,
               const unsigned short* __restrict__ WVT, const unsigned short* __restrict__ Xv,
               unsigned short* __restrict__ VT) {
  __shared__ __align__(16) char pool[131072];
  const int id = (blockIdx.x & 7) * 32 + (blockIdx.x >> 3);   // 256 % 8 == 0
  if (id < 128)
    gemm_body<unsigned short, 8, 4>(Xq, WQT, Q, id >> 2, id & 3, 1024,
                                    1024, 1024, 1024, pool, pool + 65536);
  else
    gemm_body<unsigned short, 8, 4>(Xk, WKT, Kk, (id - 128) >> 2, id & 3, 1024,
                                    1024, 1024, 1024, pool, pool + 65536);
  __syncthreads();                              // LDS safe to reuse
  gemm_body<unsigned short, 4, 4>(WVT, Xv, VT, id >> 5, id & 31, 1024,
                                  1024, 1024, 8192, pool, pool + 32768);
}

// Scores: S_b = Q_b K_b^T; 128x128 tiles over the causal lower triangle.
// 4 batches x 136 lower-tri tiles = 544 blocks (2/CU): one round + tail.
__global__ __launch_bounds__(512, 4)
void scores_gemm(const unsigned short* __restrict__ Q, const unsigned short* __restrict__ K,
                 unsigned short* __restrict__ S) {
  __shared__ __align__(16) char pool[65536];
  const int gid = (blockIdx.x & 7) * 68 + (blockIdx.x >> 3);  // 544 = 8*68
  const int bz = gid / 136, t = gid - bz * 136;
  int bm = (int)((__fsqrt_rn(8.0f * t + 1.0f) - 1.0f) * 0.5f);
  while ((bm + 1) * (bm + 2) / 2 <= t) ++bm;
  while (bm * (bm + 1) / 2 > t) --bm;
  const int bn = t - bm * (bm + 1) / 2;
  gemm_body<unsigned short, 4, 2>(Q + (long)bz * 2048 * 1024, K + (long)bz * 2048 * 1024,
                                  S + (long)bz * 2048 * 2048, bm, bn, 1024,
                                  1024, 1024, 2048, pool, pool + 32768);
}

// PV: out_b = P_b V_b; 128x128 tiles (64 KiB LDS -> 2 blocks/CU).
// Heavy+light pairing: b<256 gets bm=15-(b>>5), b>=256 gets bm=(b-256)>>5.
__global__ __launch_bounds__(512, 4)
void pv_gemm(const unsigned short* __restrict__ P, const unsigned short* __restrict__ VT,
             float* __restrict__ O) {
  __shared__ __align__(16) char pool[65536];
  const int b = blockIdx.x;
  int bm, r;
  if (b < 256) { bm = 15 - (b >> 5); r = b & 31; }
  else         { bm = (b - 256) >> 5; r = b & 31; }
  const int bn = r & 7, bz = r >> 3;
  gemm_body<float, 4, 2>(P + (long)bz * 2048 * 2048, VT + (long)bz * 2048,
                         O + (long)bz * 2048 * 1024, bm, bn, (bm + 1) * 128,
                         2048, 8192, 1024, pool, pool + 32768);
}

// ---------------- causal softmax, vectorized, register-resident -------------
__global__ __launch_bounds__(256)
void softmax_causal(unsigned short* __restrict__ P) {
  const int row = blockIdx.x;              // b*2048 + q
  const int q = row & 2047;
  unsigned short* p = P + (long)row * 2048;
  const int nfill = ((q >> 7) + 1) << 7;   // PV reads up to this 128-boundary
  const int tid = threadIdx.x;
  const int lane = tid & 63, wid = tid >> 6;
  const int i0 = tid * 8;
  __shared__ float red[8];

  float v[8];
  float lmax = -3.0e38f;
  if (i0 <= q) {                           // skip loads past causal boundary
    ushort8 v8 = *(const ushort8*)(p + i0);
#pragma unroll
    for (int j = 0; j < 8; ++j) {
      float f = bf2f(v8[j]);
      f = (i0 + j <= q) ? f : -3.0e38f;
      v[j] = f;
      lmax = fmaxf(lmax, f);
    }
  } else {
#pragma unroll
    for (int j = 0; j < 8; ++j) v[j] = -3.0e38f;
  }
#pragma unroll
  for (int off = 1; off < 64; off <<= 1)
    lmax = fmaxf(lmax, __shfl_xor(lmax, off));
  if (lane == 0) red[wid] = lmax;
  __syncthreads();
  const float mx = fmaxf(fmaxf(red[0], red[1]), fmaxf(red[2], red[3]));

  float lsum = 0.f;
#pragma unroll
  for (int j = 0; j < 8; ++j) {
    float e = __expf(v[j] - mx);           // masked lanes -> exp(-huge) = 0
    v[j] = e;
    lsum += e;
  }
#pragma unroll
  for (int off = 1; off < 64; off <<= 1)
    lsum += __shfl_xor(lsum, off);
  if (lane == 0) red[4 + wid] = lsum;
  __syncthreads();
  const float inv = 1.0f / (red[4] + red[5] + red[6] + red[7]);

  if (i0 < nfill) {
    ushort8 r;
#pragma unroll
    for (int j = 0; j < 8; ++j)
      r[j] = (i0 + j <= q) ? f2bf(v[j] * inv) : (unsigned short)0;
    *(ushort8*)(p + i0) = r;
  }
}

// ---------------------------------------------------------------------------
extern "C" void kernel_launch(void* const* d_in, const int* in_sizes, int n_in,
                              void* d_out, int out_size, void* d_ws, size_t ws_size,
                              hipStream_t stream) {
  const float* Xk = (const float*)d_in[0];
  const float* Xv = (const float*)d_in[1];
  const float* Xq = (const float*)d_in[2];
  const float* WK = (const float*)d_in[3];
  const float* WQ = (const float*)d_in[4];
  const float* WV = (const float*)d_in[5];
  float* out = (float*)d_out;

  unsigned short* ws = (unsigned short*)d_ws;
  const long NE = 8L * 1024 * 1024;          // 8192*1024 elems
  unsigned short* Xqb = ws + 0 * NE;
  unsigned short* Xkb = ws + 1 * NE;
  unsigned short* Xvb = ws + 2 * NE;
  unsigned short* Qb  = ws + 3 * NE;
  unsigned short* Kb  = ws + 4 * NE;
  unsigned short* VTb = ws + 5 * NE;
  unsigned short* WQT = ws + 6 * NE;
  unsigned short* WKT = WQT + 1024 * 1024;
  unsigned short* WVT = WKT + 1024 * 1024;
  unsigned short* Sc  = ws;                  // 2^24 elems, aliases dead Xq+Xk

  dim3 b256(256), b512(512);
  cvt3_bf16<<<12288, b256, 0, stream>>>(Xq, Xk, Xv, Xqb, Xkb, Xvb);
  wtrans3<<<dim3(32, 32, 3), dim3(32, 8), 0, stream>>>(WQ, WK, WV, WQT, WKT, WVT);
  qkvt_gemm<<<256, b512, 0, stream>>>(Xqb, WQT, Qb, Xkb, WKT, Kb, WVT, Xvb, VTb);
  scores_gemm<<<544, b512, 0, stream>>>(Qb, Kb, Sc);
  softmax_causal<<<8192, b256, 0, stream>>>(Sc);
  pv_gemm<<<512, b512, 0, stream>>>(Sc, VTb, out);
}

// Round 7
// 160.082 us; speedup vs baseline: 1.0805x; 1.0805x over previous
//
#include <hip/hip_runtime.h>
#include <stdint.h>

// ---------------------------------------------------------------------------
// AttentionHead: out = softmax_causal((Xq WQ)(Xk WK)^T / sqrt(D)) (Xv WV)
// B=4, S=2048, D=1024.  bf16 MFMA, f32 accumulate.
// Round 7: revert to round-5's proven K-loop schedule (minimal 24 ds_reads
// per K-tile, half-tile vmcnt ledger V=2LA+LB) and switch the MFMA shape to
// 32x32x16 (half the instructions, 2382 vs 2075 TF measured ceiling).
// C/D layout 32x32 (verified m74/m101): col=lane&31,
// row=(reg&3)+8*(reg>>2)+4*(lane>>5).
// ---------------------------------------------------------------------------

typedef __attribute__((ext_vector_type(8))) short short8;
typedef __attribute__((ext_vector_type(8))) unsigned short ushort8;
typedef __attribute__((ext_vector_type(16))) float f32x16;

__device__ __forceinline__ unsigned short f2bf(float f) {
  union { float f; unsigned u; } v; v.f = f;
  unsigned u = v.u + 0x7FFFu + ((v.u >> 16) & 1u);   // RNE
  return (unsigned short)(u >> 16);
}
__device__ __forceinline__ float bf2f(unsigned short h) {
  union { unsigned u; float f; } v; v.u = ((unsigned)h) << 16;
  return v.f;
}

__device__ __forceinline__ void gload16(const void* g, void* l) {
  __builtin_amdgcn_global_load_lds(
      (const __attribute__((address_space(1))) unsigned int*)g,
      (__attribute__((address_space(3))) unsigned int*)l, 16, 0, 0);
}

template<int N> __device__ __forceinline__ void vmwait() {
  static_assert(N >= 0 && N <= 8, "vmcnt range");
  if constexpr (N == 0) asm volatile("s_waitcnt vmcnt(0)" ::: "memory");
  else if constexpr (N == 1) asm volatile("s_waitcnt vmcnt(1)" ::: "memory");
  else if constexpr (N == 2) asm volatile("s_waitcnt vmcnt(2)" ::: "memory");
  else if constexpr (N == 3) asm volatile("s_waitcnt vmcnt(3)" ::: "memory");
  else if constexpr (N == 4) asm volatile("s_waitcnt vmcnt(4)" ::: "memory");
  else if constexpr (N == 5) asm volatile("s_waitcnt vmcnt(5)" ::: "memory");
  else if constexpr (N == 6) asm volatile("s_waitcnt vmcnt(6)" ::: "memory");
  else if constexpr (N == 7) asm volatile("s_waitcnt vmcnt(7)" ::: "memory");
  else asm volatile("s_waitcnt vmcnt(8)" ::: "memory");
}
__device__ __forceinline__ void barrier_() { asm volatile("s_barrier" ::: "memory"); }
__device__ __forceinline__ void lgkm0() { asm volatile("s_waitcnt lgkmcnt(0)" ::: "memory"); }

// ---------------- f32 -> bf16 convert, 3 tensors fused ----------------------
__global__ __launch_bounds__(256)
void cvt3_bf16(const float* __restrict__ Xq, const float* __restrict__ Xk,
               const float* __restrict__ Xv,
               unsigned short* __restrict__ Oq, unsigned short* __restrict__ Ok,
               unsigned short* __restrict__ Ov) {
  const int bx = blockIdx.x;
  const int op = bx >> 12, r = bx & 4095;          // 4096 blocks per tensor
  const float* in = op == 0 ? Xq : op == 1 ? Xk : Xv;
  unsigned short* out = op == 0 ? Oq : op == 1 ? Ok : Ov;
  const long i = ((long)r * 256 + threadIdx.x) * 8;
  float4 a = *(const float4*)(in + i);
  float4 b = *(const float4*)(in + i + 4);
  ushort8 rr;
  rr[0] = f2bf(a.x); rr[1] = f2bf(a.y); rr[2] = f2bf(a.z); rr[3] = f2bf(a.w);
  rr[4] = f2bf(b.x); rr[5] = f2bf(b.y); rr[6] = f2bf(b.z); rr[7] = f2bf(b.w);
  *(ushort8*)(out + i) = rr;
}

// ---------------- weight transpose x3: WT[e][k] = W[k][e]*scale -------------
__global__ __launch_bounds__(256)
void wtrans3(const float* __restrict__ WQ, const float* __restrict__ WK,
             const float* __restrict__ WV,
             unsigned short* __restrict__ WQT, unsigned short* __restrict__ WKT,
             unsigned short* __restrict__ WVT) {
  const int z = blockIdx.z;
  const float* W = z == 0 ? WQ : z == 1 ? WK : WV;
  unsigned short* WT = z == 0 ? WQT : z == 1 ? WKT : WVT;
  const float scale = z == 0 ? 0.03125f : 1.0f;    // 1/sqrt(1024) into WQT
  __shared__ float t[32][33];
  const int bk = blockIdx.x * 32, be = blockIdx.y * 32;
  const int tx = threadIdx.x, ty = threadIdx.y;    // (32,8)
#pragma unroll
  for (int j = 0; j < 32; j += 8)
    t[ty + j][tx] = W[(long)(bk + ty + j) * 1024 + (be + tx)];
  __syncthreads();
#pragma unroll
  for (int j = 0; j < 32; j += 8)
    WT[(long)(be + ty + j) * 1024 + (bk + tx)] = f2bf(t[tx][ty + j] * scale);
}

// ---------------- B^T-layout bf16 GEMM, r5 schedule + 32x32x16 MFMA ---------
// C[m][n] = sum_k A[m][k]*B[n][k].  BM=MF*32, BN=NF*64.  8 waves (2Mx4N).
// LDS [buf][khalf][row][32 cols]; 16B-slot swizzle ^((row>>1)&3).
template<typename CT, int MF, int NF>
__device__ __forceinline__ void gemm_body(const unsigned short* __restrict__ A,
                                          const unsigned short* __restrict__ B,
                                          CT* __restrict__ C,
                                          int bm, int bn, int kmax,
                                          int lda, int ldb, int ldc,
                                          char* AL, char* BL) {
  constexpr int BM = MF * 32, BN = NF * 64;
  constexpr int LA = BM / 128, LB = BN / 128;      // gloads per k-half
  constexpr int V = 2 * LA + LB;                   // steady-state vmcnt
  constexpr int MFR = MF / 2;                      // 32-row frags per wave
  constexpr int NFR = NF / 2;                      // 32-col frags per wave
  constexpr int MH = (MFR >= 2) ? MFR / 2 : 1;     // lo-half m-frags

  const int tid = threadIdx.x;                     // 0..511
  const int lane = tid & 63, wid = tid >> 6;
  const int wr = wid >> 2, wc = wid & 3;           // 2x4 wave grid
  const int fr = lane & 31;                        // row/col within 32
  const int fq = lane >> 5;                        // k-octet select
  const int srow = tid >> 2;                       // staging row 0..127
  const int scol = (((tid & 3) ^ ((tid >> 3) & 3)) << 3);  // pre-swz src col
  const int m0 = bm * BM, n0 = bn * BN;
  const int nt = kmax >> 6;

  f32x16 acc[MFR][NFR] = {};

  const unsigned short* As = A + (long)(m0 + srow) * lda + scol;
  const unsigned short* Bs = B + (long)(n0 + srow) * ldb + scol;

  auto stageA = [&](int b, int h, int kt) {        // A k-half h of tile kt
#pragma unroll
    for (int l = 0; l < LA; ++l)
      gload16(As + (long)l * 128 * lda + kt * 64 + h * 32,
              AL + b * (BM * 128) + h * (BM * 64) + l * 8192 + tid * 16);
  };
  auto stageB = [&](int b, int h, int kt) {
#pragma unroll
    for (int l = 0; l < LB; ++l)
      gload16(Bs + (long)l * 128 * ldb + kt * 64 + h * 32,
              BL + b * (BN * 128) + h * (BN * 64) + l * 8192 + tid * 16);
  };

  // 32x32x16 operand reads: lane holds row fr, 8 k-elems at octet fq.
  // k-step ks (16 k) within a 32-k half: logical 16B slot = ks*2+fq.
  auto ard = [&](int b, int kk, int m, int ks) -> short8 {
    const int row = wr * (BM / 2) + m * 32 + fr;
    const int slot = (ks * 2 + fq) ^ ((fr >> 1) & 3);
    return *(const short8*)(AL + b * (BM * 128) + kk * (BM * 64) + row * 64 + (slot << 4));
  };
  auto brd = [&](int b, int kk, int n, int ks) -> short8 {
    const int row = wc * (BN / 4) + n * 32 + fr;
    const int slot = (ks * 2 + fq) ^ ((fr >> 1) & 3);
    return *(const short8*)(BL + b * (BN * 128) + kk * (BN * 64) + row * 64 + (slot << 4));
  };

  // prologue: tile 0 -> buf 0   (issue order: A-k0, B-k0, A-k1, B-k1)
  stageA(0, 0, 0); stageB(0, 0, 0); stageA(0, 1, 0); stageB(0, 1, 0);

  for (int u = 0; u < nt; ++u) {
    const int cb = u & 1, nb = cb ^ 1;
    const bool pf = (u + 1 < nt);
    lgkm0();                                   // my ds_reads of buf nb serviced
    barrier_();                                // all waves done reading buf nb
    if (pf) { stageA(nb, 0, u + 1); vmwait<V>(); }   // retire tile-u k0 halves
    else    { vmwait<LA + LB>(); }
    barrier_();                                // k-half 0 resident for all
    short8 bfr[NFR][2], af[MH][2];
#pragma unroll
    for (int n = 0; n < NFR; ++n) { bfr[n][0] = brd(cb, 0, n, 0); bfr[n][1] = brd(cb, 0, n, 1); }
#pragma unroll
    for (int m = 0; m < MH; ++m) { af[m][0] = ard(cb, 0, m, 0); af[m][1] = ard(cb, 0, m, 1); }
    if (pf) stageB(nb, 0, u + 1);
    __builtin_amdgcn_s_setprio(1);
#pragma unroll
    for (int m = 0; m < MH; ++m)
#pragma unroll
      for (int n = 0; n < NFR; ++n) {
        acc[m][n] = __builtin_amdgcn_mfma_f32_32x32x16_bf16(af[m][0], bfr[n][0], acc[m][n], 0, 0, 0);
        acc[m][n] = __builtin_amdgcn_mfma_f32_32x32x16_bf16(af[m][1], bfr[n][1], acc[m][n], 0, 0, 0);
      }
    __builtin_amdgcn_s_setprio(0);
#pragma unroll
    for (int m = 0; m < MFR - MH; ++m) { af[m][0] = ard(cb, 0, MH + m, 0); af[m][1] = ard(cb, 0, MH + m, 1); }
    if (pf) stageA(nb, 1, u + 1);
    __builtin_amdgcn_s_setprio(1);
#pragma unroll
    for (int m = 0; m < MFR - MH; ++m)
#pragma unroll
      for (int n = 0; n < NFR; ++n) {
        acc[MH + m][n] = __builtin_amdgcn_mfma_f32_32x32x16_bf16(af[m][0], bfr[n][0], acc[MH + m][n], 0, 0, 0);
        acc[MH + m][n] = __builtin_amdgcn_mfma_f32_32x32x16_bf16(af[m][1], bfr[n][1], acc[MH + m][n], 0, 0, 0);
      }
    __builtin_amdgcn_s_setprio(0);
    if (pf) vmwait<V>(); else vmwait<0>();     // retire tile-u k1 halves
    barrier_();                                // k-half 1 resident for all
#pragma unroll
    for (int n = 0; n < NFR; ++n) { bfr[n][0] = brd(cb, 1, n, 0); bfr[n][1] = brd(cb, 1, n, 1); }
#pragma unroll
    for (int m = 0; m < MH; ++m) { af[m][0] = ard(cb, 1, m, 0); af[m][1] = ard(cb, 1, m, 1); }
    if (pf) stageB(nb, 1, u + 1);
    __builtin_amdgcn_s_setprio(1);
#pragma unroll
    for (int m = 0; m < MH; ++m)
#pragma unroll
      for (int n = 0; n < NFR; ++n) {
        acc[m][n] = __builtin_amdgcn_mfma_f32_32x32x16_bf16(af[m][0], bfr[n][0], acc[m][n], 0, 0, 0);
        acc[m][n] = __builtin_amdgcn_mfma_f32_32x32x16_bf16(af[m][1], bfr[n][1], acc[m][n], 0, 0, 0);
      }
    __builtin_amdgcn_s_setprio(0);
#pragma unroll
    for (int m = 0; m < MFR - MH; ++m) { af[m][0] = ard(cb, 1, MH + m, 0); af[m][1] = ard(cb, 1, MH + m, 1); }
    __builtin_amdgcn_s_setprio(1);
#pragma unroll
    for (int m = 0; m < MFR - MH; ++m)
#pragma unroll
      for (int n = 0; n < NFR; ++n) {
        acc[MH + m][n] = __builtin_amdgcn_mfma_f32_32x32x16_bf16(af[m][0], bfr[n][0], acc[MH + m][n], 0, 0, 0);
        acc[MH + m][n] = __builtin_amdgcn_mfma_f32_32x32x16_bf16(af[m][1], bfr[n][1], acc[MH + m][n], 0, 0, 0);
      }
    __builtin_amdgcn_s_setprio(0);
  }

  // C/D 32x32 layout (m74/m101): col=lane&31, row=(reg&3)+8*(reg>>2)+4*(lane>>5)
#pragma unroll
  for (int m = 0; m < MFR; ++m) {
    const int row0 = m0 + wr * (BM / 2) + m * 32 + fq * 4;
#pragma unroll
    for (int n = 0; n < NFR; ++n) {
      const int col = n0 + wc * (BN / 4) + n * 32 + fr;
#pragma unroll
      for (int r = 0; r < 16; ++r) {
        const int row = row0 + (r & 3) + 8 * (r >> 2);
        float v = acc[m][n][r];
        if constexpr (sizeof(CT) == 2)
          C[(long)row * ldc + col] = (CT)f2bf(v);
        else
          C[(long)row * ldc + col] = (CT)v;
      }
    }
  }
}

// Persistent Q/K + VT: 256 blocks.  Each block: one 256^2 Q-or-K tile
// (K=1024), then one 128x256 VT half-tile.  1.5 T_block each, no tail.
__global__ __launch_bounds__(512, 2)
void qkvt_gemm(const unsigned short* __restrict__ Xq, const unsigned short* __restrict__ WQT,
               unsigned short* __restrict__ Q,
               const unsigned short* __restrict__ Xk, const unsigned short* __restrict__ WKT,
               unsigned short* __restrict__ Kk,
               const unsigned short* __restrict__ WVT, const unsigned short* __restrict__ Xv,
               unsigned short* __restrict__ VT) {
  __shared__ __align__(16) char pool[131072];
  const int id = (blockIdx.x & 7) * 32 + (blockIdx.x >> 3);   // 256 % 8 == 0
  if (id < 128)
    gemm_body<unsigned short, 8, 4>(Xq, WQT, Q, id >> 2, id & 3, 1024,
                                    1024, 1024, 1024, pool, pool + 65536);
  else
    gemm_body<unsigned short, 8, 4>(Xk, WKT, Kk, (id - 128) >> 2, id & 3, 1024,
                                    1024, 1024, 1024, pool, pool + 65536);
  __syncthreads();                              // LDS safe to reuse
  gemm_body<unsigned short, 4, 4>(WVT, Xv, VT, id >> 5, id & 31, 1024,
                                  1024, 1024, 8192, pool, pool + 32768);
}

// Scores: S_b = Q_b K_b^T; 128x128 tiles over the causal lower triangle.
// 4 batches x 136 lower-tri tiles = 544 blocks (2/CU): one round + tail.
__global__ __launch_bounds__(512, 4)
void scores_gemm(const unsigned short* __restrict__ Q, const unsigned short* __restrict__ K,
                 unsigned short* __restrict__ S) {
  __shared__ __align__(16) char pool[65536];
  const int gid = (blockIdx.x & 7) * 68 + (blockIdx.x >> 3);  // 544 = 8*68
  const int bz = gid / 136, t = gid - bz * 136;
  int bm = (int)((__fsqrt_rn(8.0f * t + 1.0f) - 1.0f) * 0.5f);
  while ((bm + 1) * (bm + 2) / 2 <= t) ++bm;
  while (bm * (bm + 1) / 2 > t) --bm;
  const int bn = t - bm * (bm + 1) / 2;
  gemm_body<unsigned short, 4, 2>(Q + (long)bz * 2048 * 1024, K + (long)bz * 2048 * 1024,
                                  S + (long)bz * 2048 * 2048, bm, bn, 1024,
                                  1024, 1024, 2048, pool, pool + 32768);
}

// PV: out_b = P_b V_b; 128x128 tiles (64 KiB LDS -> 2 blocks/CU).
// Heavy+light pairing: b<256 gets bm=15-(b>>5), b>=256 gets bm=(b-256)>>5.
__global__ __launch_bounds__(512, 4)
void pv_gemm(const unsigned short* __restrict__ P, const unsigned short* __restrict__ VT,
             float* __restrict__ O) {
  __shared__ __align__(16) char pool[65536];
  const int b = blockIdx.x;
  int bm, r;
  if (b < 256) { bm = 15 - (b >> 5); r = b & 31; }
  else         { bm = (b - 256) >> 5; r = b & 31; }
  const int bn = r & 7, bz = r >> 3;
  gemm_body<float, 4, 2>(P + (long)bz * 2048 * 2048, VT + (long)bz * 2048,
                         O + (long)bz * 2048 * 1024, bm, bn, (bm + 1) * 128,
                         2048, 8192, 1024, pool, pool + 32768);
}

// ---------------- causal softmax, vectorized, register-resident -------------
__global__ __launch_bounds__(256)
void softmax_causal(unsigned short* __restrict__ P) {
  const int row = blockIdx.x;              // b*2048 + q
  const int q = row & 2047;
  unsigned short* p = P + (long)row * 2048;
  const int nfill = ((q >> 7) + 1) << 7;   // PV reads up to this 128-boundary
  const int tid = threadIdx.x;
  const int lane = tid & 63, wid = tid >> 6;
  const int i0 = tid * 8;
  __shared__ float red[8];

  float v[8];
  float lmax = -3.0e38f;
  if (i0 <= q) {                           // skip loads past causal boundary
    ushort8 v8 = *(const ushort8*)(p + i0);
#pragma unroll
    for (int j = 0; j < 8; ++j) {
      float f = bf2f(v8[j]);
      f = (i0 + j <= q) ? f : -3.0e38f;
      v[j] = f;
      lmax = fmaxf(lmax, f);
    }
  } else {
#pragma unroll
    for (int j = 0; j < 8; ++j) v[j] = -3.0e38f;
  }
#pragma unroll
  for (int off = 1; off < 64; off <<= 1)
    lmax = fmaxf(lmax, __shfl_xor(lmax, off));
  if (lane == 0) red[wid] = lmax;
  __syncthreads();
  const float mx = fmaxf(fmaxf(red[0], red[1]), fmaxf(red[2], red[3]));

  float lsum = 0.f;
#pragma unroll
  for (int j = 0; j < 8; ++j) {
    float e = __expf(v[j] - mx);           // masked lanes -> exp(-huge) = 0
    v[j] = e;
    lsum += e;
  }
#pragma unroll
  for (int off = 1; off < 64; off <<= 1)
    lsum += __shfl_xor(lsum, off);
  if (lane == 0) red[4 + wid] = lsum;
  __syncthreads();
  const float inv = 1.0f / (red[4] + red[5] + red[6] + red[7]);

  if (i0 < nfill) {
    ushort8 r;
#pragma unroll
    for (int j = 0; j < 8; ++j)
      r[j] = (i0 + j <= q) ? f2bf(v[j] * inv) : (unsigned short)0;
    *(ushort8*)(p + i0) = r;
  }
}

// ---------------------------------------------------------------------------
extern "C" void kernel_launch(void* const* d_in, const int* in_sizes, int n_in,
                              void* d_out, int out_size, void* d_ws, size_t ws_size,
                              hipStream_t stream) {
  const float* Xk = (const float*)d_in[0];
  const float* Xv = (const float*)d_in[1];
  const float* Xq = (const float*)d_in[2];
  const float* WK = (const float*)d_in[3];
  const float* WQ = (const float*)d_in[4];
  const float* WV = (const float*)d_in[5];
  float* out = (float*)d_out;

  unsigned short* ws = (unsigned short*)d_ws;
  const long NE = 8L * 1024 * 1024;          // 8192*1024 elems
  unsigned short* Xqb = ws + 0 * NE;
  unsigned short* Xkb = ws + 1 * NE;
  unsigned short* Xvb = ws + 2 * NE;
  unsigned short* Qb  = ws + 3 * NE;
  unsigned short* Kb  = ws + 4 * NE;
  unsigned short* VTb = ws + 5 * NE;
  unsigned short* WQT = ws + 6 * NE;
  unsigned short* WKT = WQT + 1024 * 1024;
  unsigned short* WVT = WKT + 1024 * 1024;
  unsigned short* Sc  = ws;                  // 2^24 elems, aliases dead Xq+Xk

  dim3 b256(256), b512(512);
  cvt3_bf16<<<12288, b256, 0, stream>>>(Xq, Xk, Xv, Xqb, Xkb, Xvb);
  wtrans3<<<dim3(32, 32, 3), dim3(32, 8), 0, stream>>>(WQ, WK, WV, WQT, WKT, WVT);
  qkvt_gemm<<<256, b512, 0, stream>>>(Xqb, WQT, Qb, Xkb, WKT, Kb, WVT, Xvb, VTb);
  scores_gemm<<<544, b512, 0, stream>>>(Qb, Kb, Sc);
  softmax_causal<<<8192, b256, 0, stream>>>(Sc);
  pv_gemm<<<512, b512, 0, stream>>>(Sc, VTb, out);
}

// Round 8
// 159.985 us; speedup vs baseline: 1.0812x; 1.0006x over previous
//
#include <hip/hip_runtime.h>
#include <stdint.h>

// ---------------------------------------------------------------------------
// AttentionHead: out = softmax_causal((Xq WQ)(Xk WK)^T / sqrt(D)) (Xv WV)
// B=4, S=2048, D=1024.  bf16 MFMA (32x32x16), f32 accumulate.
// Round 8: fixed bank-swizzle key for the 32x32 fragment reads.
//   key = ((fr>>1)&3) ^ ((fr>>3)&2)   [adds row bit-4 so interleaved
//   quarter-wave groups {l,l+16,l+32,l+48} hit 4 distinct 16B slots]
// Verified conflict-free under both contiguous and interleaved 16-lane
// grouping models.  Source pre-swizzle matches (both-sides involution).
// ---------------------------------------------------------------------------

typedef __attribute__((ext_vector_type(8))) short short8;
typedef __attribute__((ext_vector_type(8))) unsigned short ushort8;
typedef __attribute__((ext_vector_type(16))) float f32x16;

__device__ __forceinline__ unsigned short f2bf(float f) {
  union { float f; unsigned u; } v; v.f = f;
  unsigned u = v.u + 0x7FFFu + ((v.u >> 16) & 1u);   // RNE
  return (unsigned short)(u >> 16);
}
__device__ __forceinline__ float bf2f(unsigned short h) {
  union { unsigned u; float f; } v; v.u = ((unsigned)h) << 16;
  return v.f;
}

__device__ __forceinline__ void gload16(const void* g, void* l) {
  __builtin_amdgcn_global_load_lds(
      (const __attribute__((address_space(1))) unsigned int*)g,
      (__attribute__((address_space(3))) unsigned int*)l, 16, 0, 0);
}

template<int N> __device__ __forceinline__ void vmwait() {
  static_assert(N >= 0 && N <= 8, "vmcnt range");
  if constexpr (N == 0) asm volatile("s_waitcnt vmcnt(0)" ::: "memory");
  else if constexpr (N == 1) asm volatile("s_waitcnt vmcnt(1)" ::: "memory");
  else if constexpr (N == 2) asm volatile("s_waitcnt vmcnt(2)" ::: "memory");
  else if constexpr (N == 3) asm volatile("s_waitcnt vmcnt(3)" ::: "memory");
  else if constexpr (N == 4) asm volatile("s_waitcnt vmcnt(4)" ::: "memory");
  else if constexpr (N == 5) asm volatile("s_waitcnt vmcnt(5)" ::: "memory");
  else if constexpr (N == 6) asm volatile("s_waitcnt vmcnt(6)" ::: "memory");
  else if constexpr (N == 7) asm volatile("s_waitcnt vmcnt(7)" ::: "memory");
  else asm volatile("s_waitcnt vmcnt(8)" ::: "memory");
}
__device__ __forceinline__ void barrier_() { asm volatile("s_barrier" ::: "memory"); }
__device__ __forceinline__ void lgkm0() { asm volatile("s_waitcnt lgkmcnt(0)" ::: "memory"); }

// ---------------- f32 -> bf16 convert, 3 tensors fused ----------------------
__global__ __launch_bounds__(256)
void cvt3_bf16(const float* __restrict__ Xq, const float* __restrict__ Xk,
               const float* __restrict__ Xv,
               unsigned short* __restrict__ Oq, unsigned short* __restrict__ Ok,
               unsigned short* __restrict__ Ov) {
  const int bx = blockIdx.x;
  const int op = bx >> 12, r = bx & 4095;          // 4096 blocks per tensor
  const float* in = op == 0 ? Xq : op == 1 ? Xk : Xv;
  unsigned short* out = op == 0 ? Oq : op == 1 ? Ok : Ov;
  const long i = ((long)r * 256 + threadIdx.x) * 8;
  float4 a = *(const float4*)(in + i);
  float4 b = *(const float4*)(in + i + 4);
  ushort8 rr;
  rr[0] = f2bf(a.x); rr[1] = f2bf(a.y); rr[2] = f2bf(a.z); rr[3] = f2bf(a.w);
  rr[4] = f2bf(b.x); rr[5] = f2bf(b.y); rr[6] = f2bf(b.z); rr[7] = f2bf(b.w);
  *(ushort8*)(out + i) = rr;
}

// ---------------- weight transpose x3: WT[e][k] = W[k][e]*scale -------------
__global__ __launch_bounds__(256)
void wtrans3(const float* __restrict__ WQ, const float* __restrict__ WK,
             const float* __restrict__ WV,
             unsigned short* __restrict__ WQT, unsigned short* __restrict__ WKT,
             unsigned short* __restrict__ WVT) {
  const int z = blockIdx.z;
  const float* W = z == 0 ? WQ : z == 1 ? WK : WV;
  unsigned short* WT = z == 0 ? WQT : z == 1 ? WKT : WVT;
  const float scale = z == 0 ? 0.03125f : 1.0f;    // 1/sqrt(1024) into WQT
  __shared__ float t[32][33];
  const int bk = blockIdx.x * 32, be = blockIdx.y * 32;
  const int tx = threadIdx.x, ty = threadIdx.y;    // (32,8)
#pragma unroll
  for (int j = 0; j < 32; j += 8)
    t[ty + j][tx] = W[(long)(bk + ty + j) * 1024 + (be + tx)];
  __syncthreads();
#pragma unroll
  for (int j = 0; j < 32; j += 8)
    WT[(long)(be + ty + j) * 1024 + (bk + tx)] = f2bf(t[tx][ty + j] * scale);
}

// ---------------- B^T-layout bf16 GEMM, r5 schedule + 32x32x16 MFMA ---------
// C[m][n] = sum_k A[m][k]*B[n][k].  BM=MF*32, BN=NF*64.  8 waves (2Mx4N).
// LDS [buf][khalf][row][32 cols]; 16B-slot swizzle ^(((row>>1)&3)^((row>>3)&2)).
template<typename CT, int MF, int NF>
__device__ __forceinline__ void gemm_body(const unsigned short* __restrict__ A,
                                          const unsigned short* __restrict__ B,
                                          CT* __restrict__ C,
                                          int bm, int bn, int kmax,
                                          int lda, int ldb, int ldc,
                                          char* AL, char* BL) {
  constexpr int BM = MF * 32, BN = NF * 64;
  constexpr int LA = BM / 128, LB = BN / 128;      // gloads per k-half
  constexpr int V = 2 * LA + LB;                   // steady-state vmcnt
  constexpr int MFR = MF / 2;                      // 32-row frags per wave
  constexpr int NFR = NF / 2;                      // 32-col frags per wave
  constexpr int MH = (MFR >= 2) ? MFR / 2 : 1;     // lo-half m-frags

  const int tid = threadIdx.x;                     // 0..511
  const int lane = tid & 63, wid = tid >> 6;
  const int wr = wid >> 2, wc = wid & 3;           // 2x4 wave grid
  const int fr = lane & 31;                        // row/col within 32
  const int fq = lane >> 5;                        // k-octet select
  const int key = ((fr >> 1) & 3) ^ ((fr >> 3) & 2);   // bank-swizzle key
  const int srow = tid >> 2;                       // staging row 0..127
  const int scol = (((tid & 3) ^ ((tid >> 3) & 3) ^ ((tid >> 5) & 2)) << 3);
  const int m0 = bm * BM, n0 = bn * BN;
  const int nt = kmax >> 6;

  f32x16 acc[MFR][NFR] = {};

  const unsigned short* As = A + (long)(m0 + srow) * lda + scol;
  const unsigned short* Bs = B + (long)(n0 + srow) * ldb + scol;

  auto stageA = [&](int b, int h, int kt) {        // A k-half h of tile kt
#pragma unroll
    for (int l = 0; l < LA; ++l)
      gload16(As + (long)l * 128 * lda + kt * 64 + h * 32,
              AL + b * (BM * 128) + h * (BM * 64) + l * 8192 + tid * 16);
  };
  auto stageB = [&](int b, int h, int kt) {
#pragma unroll
    for (int l = 0; l < LB; ++l)
      gload16(Bs + (long)l * 128 * ldb + kt * 64 + h * 32,
              BL + b * (BN * 128) + h * (BN * 64) + l * 8192 + tid * 16);
  };

  // 32x32x16 operand reads: lane holds row fr, 8 k-elems at octet fq.
  // k-step ks (16 k) within a 32-k half: logical 16B slot = ks*2+fq.
  auto ard = [&](int b, int kk, int m, int ks) -> short8 {
    const int row = wr * (BM / 2) + m * 32 + fr;
    const int slot = (ks * 2 + fq) ^ key;
    return *(const short8*)(AL + b * (BM * 128) + kk * (BM * 64) + row * 64 + (slot << 4));
  };
  auto brd = [&](int b, int kk, int n, int ks) -> short8 {
    const int row = wc * (BN / 4) + n * 32 + fr;
    const int slot = (ks * 2 + fq) ^ key;
    return *(const short8*)(BL + b * (BN * 128) + kk * (BN * 64) + row * 64 + (slot << 4));
  };

  // prologue: tile 0 -> buf 0   (issue order: A-k0, B-k0, A-k1, B-k1)
  stageA(0, 0, 0); stageB(0, 0, 0); stageA(0, 1, 0); stageB(0, 1, 0);

  for (int u = 0; u < nt; ++u) {
    const int cb = u & 1, nb = cb ^ 1;
    const bool pf = (u + 1 < nt);
    lgkm0();                                   // my ds_reads of buf nb serviced
    barrier_();                                // all waves done reading buf nb
    if (pf) { stageA(nb, 0, u + 1); vmwait<V>(); }   // retire tile-u k0 halves
    else    { vmwait<LA + LB>(); }
    barrier_();                                // k-half 0 resident for all
    short8 bfr[NFR][2], af[MH][2];
#pragma unroll
    for (int n = 0; n < NFR; ++n) { bfr[n][0] = brd(cb, 0, n, 0); bfr[n][1] = brd(cb, 0, n, 1); }
#pragma unroll
    for (int m = 0; m < MH; ++m) { af[m][0] = ard(cb, 0, m, 0); af[m][1] = ard(cb, 0, m, 1); }
    if (pf) stageB(nb, 0, u + 1);
    __builtin_amdgcn_s_setprio(1);
#pragma unroll
    for (int m = 0; m < MH; ++m)
#pragma unroll
      for (int n = 0; n < NFR; ++n) {
        acc[m][n] = __builtin_amdgcn_mfma_f32_32x32x16_bf16(af[m][0], bfr[n][0], acc[m][n], 0, 0, 0);
        acc[m][n] = __builtin_amdgcn_mfma_f32_32x32x16_bf16(af[m][1], bfr[n][1], acc[m][n], 0, 0, 0);
      }
    __builtin_amdgcn_s_setprio(0);
#pragma unroll
    for (int m = 0; m < MFR - MH; ++m) { af[m][0] = ard(cb, 0, MH + m, 0); af[m][1] = ard(cb, 0, MH + m, 1); }
    if (pf) stageA(nb, 1, u + 1);
    __builtin_amdgcn_s_setprio(1);
#pragma unroll
    for (int m = 0; m < MFR - MH; ++m)
#pragma unroll
      for (int n = 0; n < NFR; ++n) {
        acc[MH + m][n] = __builtin_amdgcn_mfma_f32_32x32x16_bf16(af[m][0], bfr[n][0], acc[MH + m][n], 0, 0, 0);
        acc[MH + m][n] = __builtin_amdgcn_mfma_f32_32x32x16_bf16(af[m][1], bfr[n][1], acc[MH + m][n], 0, 0, 0);
      }
    __builtin_amdgcn_s_setprio(0);
    if (pf) vmwait<V>(); else vmwait<0>();     // retire tile-u k1 halves
    barrier_();                                // k-half 1 resident for all
#pragma unroll
    for (int n = 0; n < NFR; ++n) { bfr[n][0] = brd(cb, 1, n, 0); bfr[n][1] = brd(cb, 1, n, 1); }
#pragma unroll
    for (int m = 0; m < MH; ++m) { af[m][0] = ard(cb, 1, m, 0); af[m][1] = ard(cb, 1, m, 1); }
    if (pf) stageB(nb, 1, u + 1);
    __builtin_amdgcn_s_setprio(1);
#pragma unroll
    for (int m = 0; m < MH; ++m)
#pragma unroll
      for (int n = 0; n < NFR; ++n) {
        acc[m][n] = __builtin_amdgcn_mfma_f32_32x32x16_bf16(af[m][0], bfr[n][0], acc[m][n], 0, 0, 0);
        acc[m][n] = __builtin_amdgcn_mfma_f32_32x32x16_bf16(af[m][1], bfr[n][1], acc[m][n], 0, 0, 0);
      }
    __builtin_amdgcn_s_setprio(0);
#pragma unroll
    for (int m = 0; m < MFR - MH; ++m) { af[m][0] = ard(cb, 1, MH + m, 0); af[m][1] = ard(cb, 1, MH + m, 1); }
    __builtin_amdgcn_s_setprio(1);
#pragma unroll
    for (int m = 0; m < MFR - MH; ++m)
#pragma unroll
      for (int n = 0; n < NFR; ++n) {
        acc[MH + m][n] = __builtin_amdgcn_mfma_f32_32x32x16_bf16(af[m][0], bfr[n][0], acc[MH + m][n], 0, 0, 0);
        acc[MH + m][n] = __builtin_amdgcn_mfma_f32_32x32x16_bf16(af[m][1], bfr[n][1], acc[MH + m][n], 0, 0, 0);
      }
    __builtin_amdgcn_s_setprio(0);
  }

  // C/D 32x32 layout (m74/m101): col=lane&31, row=(reg&3)+8*(reg>>2)+4*(lane>>5)
#pragma unroll
  for (int m = 0; m < MFR; ++m) {
    const int row0 = m0 + wr * (BM / 2) + m * 32 + fq * 4;
#pragma unroll
    for (int n = 0; n < NFR; ++n) {
      const int col = n0 + wc * (BN / 4) + n * 32 + fr;
#pragma unroll
      for (int r = 0; r < 16; ++r) {
        const int row = row0 + (r & 3) + 8 * (r >> 2);
        float v = acc[m][n][r];
        if constexpr (sizeof(CT) == 2)
          C[(long)row * ldc + col] = (CT)f2bf(v);
        else
          C[(long)row * ldc + col] = (CT)v;
      }
    }
  }
}

// Persistent Q/K + VT: 256 blocks.  Each block: one 256^2 Q-or-K tile
// (K=1024), then one 128x256 VT half-tile.  1.5 T_block each, no tail.
__global__ __launch_bounds__(512, 2)
void qkvt_gemm(const unsigned short* __restrict__ Xq, const unsigned short* __restrict__ WQT,
               unsigned short* __restrict__ Q,
               const unsigned short* __restrict__ Xk, const unsigned short* __restrict__ WKT,
               unsigned short* __restrict__ Kk,
               const unsigned short* __restrict__ WVT, const unsigned short* __restrict__ Xv,
               unsigned short* __restrict__ VT) {
  __shared__ __align__(16) char pool[131072];
  const int id = (blockIdx.x & 7) * 32 + (blockIdx.x >> 3);   // 256 % 8 == 0
  if (id < 128)
    gemm_body<unsigned short, 8, 4>(Xq, WQT, Q, id >> 2, id & 3, 1024,
                                    1024, 1024, 1024, pool, pool + 65536);
  else
    gemm_body<unsigned short, 8, 4>(Xk, WKT, Kk, (id - 128) >> 2, id & 3, 1024,
                                    1024, 1024, 1024, pool, pool + 65536);
  __syncthreads();                              // LDS safe to reuse
  gemm_body<unsigned short, 4, 4>(WVT, Xv, VT, id >> 5, id & 31, 1024,
                                  1024, 1024, 8192, pool, pool + 32768);
}

// Scores: S_b = Q_b K_b^T; 128x128 tiles over the causal lower triangle.
// 4 batches x 136 lower-tri tiles = 544 blocks (2/CU): one round + tail.
__global__ __launch_bounds__(512, 4)
void scores_gemm(const unsigned short* __restrict__ Q, const unsigned short* __restrict__ K,
                 unsigned short* __restrict__ S) {
  __shared__ __align__(16) char pool[65536];
  const int gid = (blockIdx.x & 7) * 68 + (blockIdx.x >> 3);  // 544 = 8*68
  const int bz = gid / 136, t = gid - bz * 136;
  int bm = (int)((__fsqrt_rn(8.0f * t + 1.0f) - 1.0f) * 0.5f);
  while ((bm + 1) * (bm + 2) / 2 <= t) ++bm;
  while (bm * (bm + 1) / 2 > t) --bm;
  const int bn = t - bm * (bm + 1) / 2;
  gemm_body<unsigned short, 4, 2>(Q + (long)bz * 2048 * 1024, K + (long)bz * 2048 * 1024,
                                  S + (long)bz * 2048 * 2048, bm, bn, 1024,
                                  1024, 1024, 2048, pool, pool + 32768);
}

// PV: out_b = P_b V_b; 128x128 tiles (64 KiB LDS -> 2 blocks/CU).
// Heavy+light pairing: b<256 gets bm=15-(b>>5), b>=256 gets bm=(b-256)>>5.
__global__ __launch_bounds__(512, 4)
void pv_gemm(const unsigned short* __restrict__ P, const unsigned short* __restrict__ VT,
             float* __restrict__ O) {
  __shared__ __align__(16) char pool[65536];
  const int b = blockIdx.x;
  int bm, r;
  if (b < 256) { bm = 15 - (b >> 5); r = b & 31; }
  else         { bm = (b - 256) >> 5; r = b & 31; }
  const int bn = r & 7, bz = r >> 3;
  gemm_body<float, 4, 2>(P + (long)bz * 2048 * 2048, VT + (long)bz * 2048,
                         O + (long)bz * 2048 * 1024, bm, bn, (bm + 1) * 128,
                         2048, 8192, 1024, pool, pool + 32768);
}

// ---------------- causal softmax, vectorized, register-resident -------------
__global__ __launch_bounds__(256)
void softmax_causal(unsigned short* __restrict__ P) {
  const int row = blockIdx.x;              // b*2048 + q
  const int q = row & 2047;
  unsigned short* p = P + (long)row * 2048;
  const int nfill = ((q >> 7) + 1) << 7;   // PV reads up to this 128-boundary
  const int tid = threadIdx.x;
  const int lane = tid & 63, wid = tid >> 6;
  const int i0 = tid * 8;
  __shared__ float red[8];

  float v[8];
  float lmax = -3.0e38f;
  if (i0 <= q) {                           // skip loads past causal boundary
    ushort8 v8 = *(const ushort8*)(p + i0);
#pragma unroll
    for (int j = 0; j < 8; ++j) {
      float f = bf2f(v8[j]);
      f = (i0 + j <= q) ? f : -3.0e38f;
      v[j] = f;
      lmax = fmaxf(lmax, f);
    }
  } else {
#pragma unroll
    for (int j = 0; j < 8; ++j) v[j] = -3.0e38f;
  }
#pragma unroll
  for (int off = 1; off < 64; off <<= 1)
    lmax = fmaxf(lmax, __shfl_xor(lmax, off));
  if (lane == 0) red[wid] = lmax;
  __syncthreads();
  const float mx = fmaxf(fmaxf(red[0], red[1]), fmaxf(red[2], red[3]));

  float lsum = 0.f;
#pragma unroll
  for (int j = 0; j < 8; ++j) {
    float e = __expf(v[j] - mx);           // masked lanes -> exp(-huge) = 0
    v[j] = e;
    lsum += e;
  }
#pragma unroll
  for (int off = 1; off < 64; off <<= 1)
    lsum += __shfl_xor(lsum, off);
  if (lane == 0) red[4 + wid] = lsum;
  __syncthreads();
  const float inv = 1.0f / (red[4] + red[5] + red[6] + red[7]);

  if (i0 < nfill) {
    ushort8 r;
#pragma unroll
    for (int j = 0; j < 8; ++j)
      r[j] = (i0 + j <= q) ? f2bf(v[j] * inv) : (unsigned short)0;
    *(ushort8*)(p + i0) = r;
  }
}

// ---------------------------------------------------------------------------
extern "C" void kernel_launch(void* const* d_in, const int* in_sizes, int n_in,
                              void* d_out, int out_size, void* d_ws, size_t ws_size,
                              hipStream_t stream) {
  const float* Xk = (const float*)d_in[0];
  const float* Xv = (const float*)d_in[1];
  const float* Xq = (const float*)d_in[2];
  const float* WK = (const float*)d_in[3];
  const float* WQ = (const float*)d_in[4];
  const float* WV = (const float*)d_in[5];
  float* out = (float*)d_out;

  unsigned short* ws = (unsigned short*)d_ws;
  const long NE = 8L * 1024 * 1024;          // 8192*1024 elems
  unsigned short* Xqb = ws + 0 * NE;
  unsigned short* Xkb = ws + 1 * NE;
  unsigned short* Xvb = ws + 2 * NE;
  unsigned short* Qb  = ws + 3 * NE;
  unsigned short* Kb  = ws + 4 * NE;
  unsigned short* VTb = ws + 5 * NE;
  unsigned short* WQT = ws + 6 * NE;
  unsigned short* WKT = WQT + 1024 * 1024;
  unsigned short* WVT = WKT + 1024 * 1024;
  unsigned short* Sc  = ws;                  // 2^24 elems, aliases dead Xq+Xk

  dim3 b256(256), b512(512);
  cvt3_bf16<<<12288, b256, 0, stream>>>(Xq, Xk, Xv, Xqb, Xkb, Xvb);
  wtrans3<<<dim3(32, 32, 3), dim3(32, 8), 0, stream>>>(WQ, WK, WV, WQT, WKT, WVT);
  qkvt_gemm<<<256, b512, 0, stream>>>(Xqb, WQT, Qb, Xkb, WKT, Kb, WVT, Xvb, VTb);
  scores_gemm<<<544, b512, 0, stream>>>(Qb, Kb, Sc);
  softmax_causal<<<8192, b256, 0, stream>>>(Sc);
  pv_gemm<<<512, b512, 0, stream>>>(Sc, VTb, out);
}